// Round 7
// baseline (122.659 us; speedup 1.0000x reference)
//
#include <hip/hip_runtime.h>
#include <hip/hip_bf16.h>

// Supervised contrastive loss, B=8192, D=256, T=0.07, 100 classes.
//   prep:   z f32 -> bf16 (ws); zero sn/cls_cnt/gacc
//   bucket: per-class index lists
//   passA:  symmetric row/col sums of exp(z@z^T/T), upper-triangle 128x128
//           tiles. 512 blocks = 32 strip-pairs x 16 splits (2 blocks/CU).
//           8 waves (4 wr x 2 wc), per-wave 32 rows x 64 cols. A in regs
//           (reloaded <=2x per block), B staged in K-half phases (32KB,
//           DOUBLE-buffered) via global_load_lds w16 + XOR swizzle; one
//           barrier per phase. Row-sums in regs (flush per strip); col-sums
//           via per-wave LDS slices, flushed per off-diag tile (symmetry).
//   passB:  per class (100 blocks x 8 waves): async-gather members to LDS,
//           all-pairs MFMA (bitwise-equal d to passA) -> sum_same ->
//           sum_neg = sn - sum_same; pair-loss pass; atomics into gacc.
//   final:  out = gacc[0]/max(gacc[1],1)

#define BN 8192
#define DD 256
#define INV_T (1.0f / 0.07f)
#define CAPI 256
#define CAP 160

typedef __attribute__((ext_vector_type(8))) __bf16 bf16x8;
typedef __attribute__((ext_vector_type(4))) float f32x4;

typedef const __attribute__((address_space(1))) void gas_void;
typedef __attribute__((address_space(3))) void las_void;

static __device__ __forceinline__ void gld_lds16(const void* g, void* l) {
    __builtin_amdgcn_global_load_lds((gas_void*)g, (las_void*)l, 16, 0, 0);
}

static __device__ __forceinline__ unsigned short f2bf(float f) {
    unsigned int u = __builtin_bit_cast(unsigned int, f);
    u = (u + 0x7FFFu + ((u >> 16) & 1u)) >> 16;   // RNE, inputs finite
    return (unsigned short)u;
}

// ---------------- kernel 1: convert z to bf16, zero sn/cls_cnt/gacc -------
__global__ __launch_bounds__(256) void k_prep(const float* __restrict__ z,
                                              unsigned short* __restrict__ zbf,
                                              float* __restrict__ sn,
                                              int* __restrict__ cls_cnt,
                                              float* __restrict__ gacc) {
    const int gid = blockIdx.x * 256 + threadIdx.x;       // 262144 threads
    const float4* z4 = (const float4*)z;
    float4 v0 = z4[gid * 2 + 0];
    float4 v1 = z4[gid * 2 + 1];
    unsigned short r[8];
    r[0] = f2bf(v0.x); r[1] = f2bf(v0.y); r[2] = f2bf(v0.z); r[3] = f2bf(v0.w);
    r[4] = f2bf(v1.x); r[5] = f2bf(v1.y); r[6] = f2bf(v1.z); r[7] = f2bf(v1.w);
    ((uint4*)zbf)[gid] = *(const uint4*)r;
    if (gid < BN) sn[gid] = 0.f;
    if (blockIdx.x == 0) {
        if (threadIdx.x < 100) cls_cnt[threadIdx.x] = 0;
        if (threadIdx.x < 2) gacc[threadIdx.x] = 0.f;
    }
}

// ---------------- kernel 1b: bucket rows by class -------------------------
__global__ __launch_bounds__(256) void k_bucket(const int* __restrict__ labels,
                                                int* __restrict__ cls_cnt,
                                                int* __restrict__ cls_idx) {
    const int gid = blockIdx.x * 256 + threadIdx.x;
    if (gid < BN) {
        const int c = labels[gid];
        const int slot = atomicAdd(&cls_cnt[c], 1);
        if (slot < CAPI) cls_idx[c * CAPI + slot] = gid;
    }
}

// ---------------- kernel 2: symmetric tile sums of exp --------------------
// Grid 512 = 32 strip-pairs x 16 splits. 512 thr = 8 waves (4 wr x 2 wc).
__global__ __launch_bounds__(512, 4) void k_passA(const unsigned short* __restrict__ zbf,
                                                  float* __restrict__ sn) {
    __shared__ char Bb[2][32768];              // [128 cols][256B K-half], swizzled
    __shared__ float cs_lds[8][128];           // per-wave col-sum slices

    const int tid = threadIdx.x;
    const int w = tid >> 6, lane = tid & 63;
    const int l15 = lane & 15, lk = lane >> 4;
    const int wr = w >> 1, wc = w & 1;         // 4 row-groups x 2 col-groups
    const int p = blockIdx.x >> 4, q = blockIdx.x & 15;
    const int r1 = 63 - p, n0 = 64 - p;        // jobs [0,n0) -> strip p, [n0,65) -> strip r1
    const int jlo = (65 * q) >> 4, jhi = (65 * (q + 1)) >> 4;
    const char* zb = (const char*)zbf;

    bf16x8 a[2][8];
    f32x4 acc[2][4];
    float snp[2][4];

    auto jobStrip = [&](int ji) { return (ji < n0) ? p : r1; };
    auto jobTile  = [&](int ji) { return (ji < n0) ? p + ji : r1 + (ji - n0); };

    auto stage = [&](int buf, int j, int kh) {
        const char* g = zb + ((size_t)j * 128) * 512 + kh * 256;
        char* lb = Bb[buf];
#pragma unroll
        for (int r = 0; r < 4; ++r) {
            const int s = (r * 512 + tid) * 16;
            const int col = s >> 8, koff = s & 255;
            const int ksrc = koff ^ ((col & 7) << 4);   // pre-swizzled source
            gld_lds16(g + (size_t)col * 512 + ksrc, lb + s);
        }
    };
    auto loadA = [&](int s) {
#pragma unroll
        for (int m = 0; m < 2; ++m) {
            const char* ap = zb + (size_t)(s * 128 + wr * 32 + m * 16 + l15) * 512 + lk * 16;
#pragma unroll
            for (int kf = 0; kf < 8; ++kf) a[m][kf] = *(const bf16x8*)(ap + kf * 64);
        }
    };
    auto flushRows = [&](int s) {
#pragma unroll
        for (int m = 0; m < 2; ++m)
#pragma unroll
            for (int rr = 0; rr < 4; ++rr) {
                float v = snp[m][rr];
                v += __shfl_xor(v, 1, 64);
                v += __shfl_xor(v, 2, 64);
                v += __shfl_xor(v, 4, 64);
                v += __shfl_xor(v, 8, 64);
                if (l15 == 0)
                    atomicAdd(&sn[s * 128 + wr * 32 + m * 16 + lk * 4 + rr], v);
                snp[m][rr] = 0.f;
            }
    };

    int sCur = jobStrip(jlo);
    loadA(sCur);
    stage(0, jobTile(jlo), 0);
#pragma unroll
    for (int m = 0; m < 2; ++m)
#pragma unroll
        for (int rr = 0; rr < 4; ++rr) snp[m][rr] = 0.f;

    __syncthreads();                           // buf0 + A ready

    const int nph = 2 * (jhi - jlo);
    int buf = 0;
    for (int ph = 0; ph < nph; ++ph) {
        const int ji = jlo + (ph >> 1);
        const int kh = ph & 1;
        const int sNew = jobStrip(ji);
        if (sNew != sCur) {                    // strip change (kh==0 only)
            flushRows(sCur);
            loadA(sNew);
            sCur = sNew;
        }
        if (kh == 0) {
#pragma unroll
            for (int m = 0; m < 2; ++m)
#pragma unroll
                for (int n = 0; n < 4; ++n) acc[m][n] = (f32x4){0.f, 0.f, 0.f, 0.f};
        }
        if (ph + 1 < nph)
            stage(buf ^ 1, jobTile(jlo + ((ph + 1) >> 1)), (ph + 1) & 1);

        // ---- compute this K-half ----
        const char* bp0 = Bb[buf];
#pragma unroll
        for (int n = 0; n < 4; ++n) {
            const int col = wc * 64 + n * 16 + l15;
            const char* bp = bp0 + (size_t)col * 256;
            const int sw = (col & 7) << 4;
            bf16x8 b[4];
#pragma unroll
            for (int kf = 0; kf < 4; ++kf)
                b[kf] = *(const bf16x8*)(bp + ((lk * 16 + kf * 64) ^ sw));
#pragma unroll
            for (int kf = 0; kf < 4; ++kf)
#pragma unroll
                for (int m = 0; m < 2; ++m)
                    acc[m][n] = __builtin_amdgcn_mfma_f32_16x16x32_bf16(a[m][kh * 4 + kf], b[kf], acc[m][n], 0, 0, 0);
        }

        const int j = jobTile(ji);
        const bool diag = (j == sCur);
        if (kh == 1) {
            // ---- epilogue: exp, row-sums (regs), col-sums (LDS slices) ----
#pragma unroll
            for (int n = 0; n < 4; ++n) {
                const int colLocal = wc * 64 + n * 16 + l15;
                float csn = 0.f;
#pragma unroll
                for (int m = 0; m < 2; ++m) {
                    const int rowL0 = wr * 32 + m * 16 + lk * 4;
#pragma unroll
                    for (int rr = 0; rr < 4; ++rr) {
                        float e = __expf(acc[m][n][rr] * INV_T);
                        if (diag && (rowL0 + rr) == colLocal) e = 0.f;
                        snp[m][rr] += e;
                        csn += e;
                    }
                }
                csn += __shfl_xor(csn, 16, 64);
                csn += __shfl_xor(csn, 32, 64);
                if (lane < 16) cs_lds[w][wc * 64 + n * 16 + lane] = csn;
            }
        }
        __syncthreads();                       // stage done + cs slices visible
        if (kh == 1 && !diag && tid < 128) {
            const int sel = tid >> 6;          // which wc-group wrote this col
            const float v = cs_lds[sel][tid] + cs_lds[2 + sel][tid]
                          + cs_lds[4 + sel][tid] + cs_lds[6 + sel][tid];
            atomicAdd(&sn[j * 128 + tid], v);  // symmetric contribution
        }
        buf ^= 1;
    }
    flushRows(sCur);
}

// ---------------- kernel 3: per-class positive pairs ----------------------
// 100 blocks x 512 thr (8 waves). Async gather, two MFMA passes, atomics
// into gacc[0] (sum row_loss) and gacc[1] (n_valid).
__global__ __launch_bounds__(512) void k_passB(const unsigned short* __restrict__ zbf,
                                               const float* __restrict__ sn,
                                               const int* __restrict__ cls_cnt,
                                               const int* __restrict__ cls_idx,
                                               float* __restrict__ gacc) {
    __shared__ char Zc[CAP * 512];             // swizzled [row][512 B]
    __shared__ int glist[CAP];
    __shared__ float snl[CAP];
    __shared__ float sums[CAP];
    __shared__ float blkL;

    const int c = blockIdx.x;
    const int tid = threadIdx.x;
    const int w = tid >> 6, lane = tid & 63;
    const int l15 = lane & 15, lk = lane >> 4;
    const char* zb = (const char*)zbf;

    const int n_c = min(cls_cnt[c], CAP);
    const int nt = (n_c + 15) >> 4;
    const int rows_p = nt * 16;

    if (tid < CAP) glist[tid] = (tid < n_c) ? cls_idx[c * CAPI + tid] : 0;
    if (tid == 0) blkL = 0.f;
    __syncthreads();

    // async gather: one wave-instr moves 2 rows (64 lanes x 16B), swizzled src
    for (int e2 = w * 2; e2 < rows_p; e2 += 16) {
        const int row = e2 + (lane >> 5);
        const int cb = (lane & 31) * 16;
        gld_lds16(zb + (size_t)glist[row] * 512 + (cb ^ ((row & 7) << 4)),
                  (char*)Zc + e2 * 512);
    }
    __syncthreads();                           // vmcnt drained by barrier

    // ---- pass 1: sum_same ----
    for (int mi = w; mi < nt; mi += 8) {
        const int rowA = mi * 16 + l15;
        const int swa = (rowA & 7) << 4;
        bf16x8 a[8];
#pragma unroll
        for (int kf = 0; kf < 8; ++kf)
            a[kf] = *(const bf16x8*)(Zc + rowA * 512 + ((lk * 16 + kf * 64) ^ swa));
        float sp[4] = {};
        for (int nj = 0; nj < nt; ++nj) {
            const int colB = nj * 16 + l15;
            const int swb = (colB & 7) << 4;
            bf16x8 b[8];
#pragma unroll
            for (int kf = 0; kf < 8; ++kf)
                b[kf] = *(const bf16x8*)(Zc + colB * 512 + ((lk * 16 + kf * 64) ^ swb));
            f32x4 acc = {};
#pragma unroll
            for (int kf = 0; kf < 8; ++kf)
                acc = __builtin_amdgcn_mfma_f32_16x16x32_bf16(a[kf], b[kf], acc, 0, 0, 0);
#pragma unroll
            for (int rr = 0; rr < 4; ++rr) {
                const int i = mi * 16 + lk * 4 + rr;
                const float e = __expf(acc[rr] * INV_T);
                sp[rr] += (colB < n_c && i != colB) ? e : 0.f;
            }
        }
#pragma unroll
        for (int rr = 0; rr < 4; ++rr) {
            float v = sp[rr];
            v += __shfl_xor(v, 1, 64);
            v += __shfl_xor(v, 2, 64);
            v += __shfl_xor(v, 4, 64);
            v += __shfl_xor(v, 8, 64);
            if (l15 == 0) sums[mi * 16 + lk * 4 + rr] = v;
        }
    }
    __syncthreads();
    if (tid < CAP) snl[tid] = (tid < n_c) ? sn[glist[tid]] - sums[tid] : 0.f;
    __syncthreads();

    // ---- pass 2: pair losses ----
    for (int mi = w; mi < nt; mi += 8) {
        const int rowA = mi * 16 + l15;
        const int swa = (rowA & 7) << 4;
        bf16x8 a[8];
#pragma unroll
        for (int kf = 0; kf < 8; ++kf)
            a[kf] = *(const bf16x8*)(Zc + rowA * 512 + ((lk * 16 + kf * 64) ^ swa));
        float sneg[4];
#pragma unroll
        for (int rr = 0; rr < 4; ++rr) {
            const int i = mi * 16 + lk * 4 + rr;
            sneg[rr] = (i < n_c) ? snl[i] : 0.f;
        }
        float sp[4] = {};
        for (int nj = 0; nj < nt; ++nj) {
            const int colB = nj * 16 + l15;
            const int swb = (colB & 7) << 4;
            bf16x8 b[8];
#pragma unroll
            for (int kf = 0; kf < 8; ++kf)
                b[kf] = *(const bf16x8*)(Zc + colB * 512 + ((lk * 16 + kf * 64) ^ swb));
            f32x4 acc = {};
#pragma unroll
            for (int kf = 0; kf < 8; ++kf)
                acc = __builtin_amdgcn_mfma_f32_16x16x32_bf16(a[kf], b[kf], acc, 0, 0, 0);
#pragma unroll
            for (int rr = 0; rr < 4; ++rr) {
                const int i = mi * 16 + lk * 4 + rr;
                const float t = log1pf(sneg[rr] * __expf(-acc[rr] * INV_T));
                sp[rr] += (colB < n_c && i != colB) ? t : 0.f;
            }
        }
#pragma unroll
        for (int rr = 0; rr < 4; ++rr) {
            float v = sp[rr];
            v += __shfl_xor(v, 1, 64);
            v += __shfl_xor(v, 2, 64);
            v += __shfl_xor(v, 4, 64);
            v += __shfl_xor(v, 8, 64);
            const int i = mi * 16 + lk * 4 + rr;
            if (l15 == 0 && i < n_c && n_c > 1)
                atomicAdd(&blkL, v / (float)(n_c - 1));
        }
    }
    __syncthreads();
    if (tid == 0 && n_c > 1) {
        atomicAdd(&gacc[0], blkL);
        atomicAdd(&gacc[1], (float)n_c);
    }
}

// ---------------- kernel 4: final scalar ----------------------------------
__global__ void k_final(const float* __restrict__ gacc, float* __restrict__ out) {
    if (threadIdx.x == 0) {
        const float L = gacc[0], V = gacc[1];
        out[0] = (V > 0.f) ? L / fmaxf(V, 1.f) : 0.f;
    }
}

extern "C" void kernel_launch(void* const* d_in, const int* in_sizes, int n_in,
                              void* d_out, int out_size, void* d_ws, size_t ws_size,
                              hipStream_t stream) {
    const float* z      = (const float*)d_in[0];
    const int*   labels = (const int*)d_in[1];
    float* out = (float*)d_out;

    char* ws = (char*)d_ws;
    // zbf 4MB | sn 32KB | cls_cnt 1KB | cls_idx 100KB | gacc 8B
    unsigned short* zbf = (unsigned short*)ws;
    size_t off = (size_t)BN * DD * sizeof(unsigned short);
    float* sn      = (float*)(ws + off);  off += BN * sizeof(float);
    int*   cls_cnt = (int*)(ws + off);    off += 1024;
    int*   cls_idx = (int*)(ws + off);    off += 100 * CAPI * sizeof(int);
    float* gacc    = (float*)(ws + off);  off += 2 * sizeof(float);

    k_prep  <<<1024, 256, 0, stream>>>(z, zbf, sn, cls_cnt, gacc);
    k_bucket<<<32, 256, 0, stream>>>(labels, cls_cnt, cls_idx);
    k_passA <<<512, 512, 0, stream>>>(zbf, sn);
    k_passB <<<100, 512, 0, stream>>>(zbf, sn, cls_cnt, cls_idx, gacc);
    k_final <<<1, 64, 0, stream>>>(gacc, out);
}

// Round 8
// 77.993 us; speedup vs baseline: 1.5727x; 1.5727x over previous
//
#include <hip/hip_runtime.h>
#include <hip/hip_bf16.h>

// Supervised contrastive loss, B=8192, D=256, T=0.07, 100 classes.
//   prep:   z f32 -> bf16 (ws); zero cls_cnt/gacc
//   bucket: per-class index lists
//   passA:  NON-symmetric row sums of exp(z@z^T/T), diag masked. 256 blocks
//           = 64 row-tiles x 4 col-quarters (proven L2-friendly col-walk).
//           8 waves = 2 row-groups x 4 col-groups, m=4 (64 rows/wave) to
//           halve B LDS re-reads. A staged once via LDS bounce then held in
//           regs (128 VGPR); B 128-col steps double-buffered via
//           global_load_lds w16 + XOR swizzle. Per-block sn_part stores,
//           no global atomics.
//   passB:  per class (100 blocks x 8 waves): async-gather members to LDS,
//           all-pairs MFMA (bitwise-equal d to passA) -> sum_same ->
//           sum_neg = sum_all - sum_same; pair-loss pass; atomics into gacc.
//   final:  out = gacc[0]/max(gacc[1],1)

#define BN 8192
#define DD 256
#define INV_T (1.0f / 0.07f)
#define CAPI 256
#define CAP 160

typedef __attribute__((ext_vector_type(8))) __bf16 bf16x8;
typedef __attribute__((ext_vector_type(4))) float f32x4;

typedef const __attribute__((address_space(1))) void gas_void;
typedef __attribute__((address_space(3))) void las_void;

static __device__ __forceinline__ void gld_lds16(const void* g, void* l) {
    __builtin_amdgcn_global_load_lds((gas_void*)g, (las_void*)l, 16, 0, 0);
}

static __device__ __forceinline__ unsigned short f2bf(float f) {
    unsigned int u = __builtin_bit_cast(unsigned int, f);
    u = (u + 0x7FFFu + ((u >> 16) & 1u)) >> 16;   // RNE, inputs finite
    return (unsigned short)u;
}

// ---------------- kernel 1: convert z to bf16, zero cls_cnt/gacc ----------
__global__ __launch_bounds__(256) void k_prep(const float* __restrict__ z,
                                              unsigned short* __restrict__ zbf,
                                              int* __restrict__ cls_cnt,
                                              float* __restrict__ gacc) {
    const int gid = blockIdx.x * 256 + threadIdx.x;       // 262144 threads
    const float4* z4 = (const float4*)z;
    float4 v0 = z4[gid * 2 + 0];
    float4 v1 = z4[gid * 2 + 1];
    unsigned short r[8];
    r[0] = f2bf(v0.x); r[1] = f2bf(v0.y); r[2] = f2bf(v0.z); r[3] = f2bf(v0.w);
    r[4] = f2bf(v1.x); r[5] = f2bf(v1.y); r[6] = f2bf(v1.z); r[7] = f2bf(v1.w);
    ((uint4*)zbf)[gid] = *(const uint4*)r;
    if (blockIdx.x == 0) {
        if (threadIdx.x < 100) cls_cnt[threadIdx.x] = 0;
        if (threadIdx.x < 2) gacc[threadIdx.x] = 0.f;
    }
}

// ---------------- kernel 1b: bucket rows by class -------------------------
__global__ __launch_bounds__(256) void k_bucket(const int* __restrict__ labels,
                                                int* __restrict__ cls_cnt,
                                                int* __restrict__ cls_idx) {
    const int gid = blockIdx.x * 256 + threadIdx.x;
    if (gid < BN) {
        const int c = labels[gid];
        const int slot = atomicAdd(&cls_cnt[c], 1);
        if (slot < CAPI) cls_idx[c * CAPI + slot] = gid;
    }
}

// ---------------- kernel 2: row sums of exp(z z^T / T), diag masked -------
// Grid 256 = 64 row-tiles x 4 col-quarters. 512 thr = 8 waves (2 wr x 4 wc).
// Block: 128 rows x 2048 cols; per step 128 cols staged in LDS (dbuf).
__global__ __launch_bounds__(512, 2) void k_passA(const unsigned short* __restrict__ zbf,
                                                  float* __restrict__ sn_part) {
    __shared__ char Bb[2][65536];             // [128 cols][512 B], swizzled
    __shared__ float sn_lds[128];

    const int tid = threadIdx.x;
    const int by = blockIdx.x >> 2;
    const int cq = blockIdx.x & 3;
    const int rowbase = by * 128;
    const int colbase = cq * 2048;
    const char* zb = (const char*)zbf;

    auto stage = [&](int buf, int ns) {       // 128 cols x 512 B, swizzled
        const char* gB = zb + ((size_t)(colbase + ns * 128)) * 512;
        char* lb = Bb[buf];
#pragma unroll
        for (int qq = 0; qq < 8; ++qq) {
            const int s = (qq * 512 + tid) * 16;
            const int col = s >> 9, koff = s & 511;
            const int ksrc = koff ^ ((col & 7) << 4);   // pre-swizzled source
            gld_lds16(gB + (size_t)col * 512 + ksrc, lb + s);
        }
    };

    const int w = tid >> 6, lane = tid & 63;
    const int l15 = lane & 15, lk = lane >> 4;
    const int wr = w & 1, wc = w >> 1;        // 2 row-groups x 4 col-groups

    // ---- A tile via LDS bounce: stage rows once, read frags to regs ----
    {
        const char* gA = zb + (size_t)rowbase * 512;
        char* lb = Bb[0];
#pragma unroll
        for (int qq = 0; qq < 8; ++qq) {
            const int s = (qq * 512 + tid) * 16;
            const int row = s >> 9, koff = s & 511;
            const int ksrc = koff ^ ((row & 7) << 4);
            gld_lds16(gA + (size_t)row * 512 + ksrc, lb + s);
        }
    }
    __syncthreads();                          // A staged (barrier drains vmcnt)

    bf16x8 a[4][8];
#pragma unroll
    for (int m = 0; m < 4; ++m) {
        const int row = wr * 64 + m * 16 + l15;
        const int sw = (row & 7) << 4;
#pragma unroll
        for (int kf = 0; kf < 8; ++kf)
            a[m][kf] = *(const bf16x8*)(Bb[0] + row * 512 + ((lk * 16 + kf * 64) ^ sw));
    }
    int iglob[4][4];
#pragma unroll
    for (int m = 0; m < 4; ++m)
#pragma unroll
        for (int rr = 0; rr < 4; ++rr)
            iglob[m][rr] = rowbase + wr * 64 + m * 16 + lk * 4 + rr;

    if (tid < 128) sn_lds[tid] = 0.f;
    float snp[4][4] = {};

    __syncthreads();                          // A-frag reads complete
    stage(0, 0);
    __syncthreads();                          // buf0 ready

    for (int ns = 0; ns < 16; ++ns) {
        const int buf = ns & 1;
        if (ns < 15) stage(buf ^ 1, ns + 1);
        const char* bp0 = Bb[buf];
#pragma unroll
        for (int n = 0; n < 2; ++n) {
            const int colL = wc * 32 + n * 16 + l15;
            const char* bp = bp0 + (size_t)colL * 512;
            const int sw = (colL & 7) << 4;
            bf16x8 b[8];
#pragma unroll
            for (int kf = 0; kf < 8; ++kf)
                b[kf] = *(const bf16x8*)(bp + ((lk * 16 + kf * 64) ^ sw));
            const int jj = colbase + ns * 128 + colL;
#pragma unroll
            for (int m = 0; m < 4; ++m) {
                f32x4 acc = {};
#pragma unroll
                for (int kf = 0; kf < 8; ++kf)
                    acc = __builtin_amdgcn_mfma_f32_16x16x32_bf16(a[m][kf], b[kf], acc, 0, 0, 0);
#pragma unroll
                for (int rr = 0; rr < 4; ++rr) {
                    float e = __expf(acc[rr] * INV_T);
                    if (iglob[m][rr] == jj) e = 0.f;     // mask diagonal
                    snp[m][rr] += e;
                }
            }
        }
        __syncthreads();
    }

    // reduce across the 16 l15 lanes sharing each row, combine wc-groups in LDS
#pragma unroll
    for (int m = 0; m < 4; ++m) {
#pragma unroll
        for (int rr = 0; rr < 4; ++rr) {
            float v = snp[m][rr];
            v += __shfl_xor(v, 1, 64);
            v += __shfl_xor(v, 2, 64);
            v += __shfl_xor(v, 4, 64);
            v += __shfl_xor(v, 8, 64);
            if (l15 == 0)
                atomicAdd(&sn_lds[wr * 64 + m * 16 + lk * 4 + rr], v);
        }
    }
    __syncthreads();
    if (tid < 128)
        sn_part[(size_t)cq * BN + rowbase + tid] = sn_lds[tid];
}

// ---------------- kernel 3: per-class positive pairs ----------------------
// 100 blocks x 512 thr (8 waves). Async gather, two MFMA passes, atomics
// into gacc[0] (sum row_loss) and gacc[1] (n_valid).
__global__ __launch_bounds__(512) void k_passB(const unsigned short* __restrict__ zbf,
                                               const float* __restrict__ sn_part,
                                               const int* __restrict__ cls_cnt,
                                               const int* __restrict__ cls_idx,
                                               float* __restrict__ gacc) {
    __shared__ char Zc[CAP * 512];             // swizzled [row][512 B]
    __shared__ int glist[CAP];
    __shared__ float snl[CAP];
    __shared__ float sums[CAP];
    __shared__ float blkL;

    const int c = blockIdx.x;
    const int tid = threadIdx.x;
    const int w = tid >> 6, lane = tid & 63;
    const int l15 = lane & 15, lk = lane >> 4;
    const char* zb = (const char*)zbf;

    const int n_c = min(cls_cnt[c], CAP);
    const int nt = (n_c + 15) >> 4;
    const int rows_p = nt * 16;

    if (tid < CAP) glist[tid] = (tid < n_c) ? cls_idx[c * CAPI + tid] : 0;
    if (tid == 0) blkL = 0.f;
    __syncthreads();

    // async gather: one wave-instr moves 2 rows (64 lanes x 16B), swizzled src
    for (int e2 = w * 2; e2 < rows_p; e2 += 16) {
        const int row = e2 + (lane >> 5);
        const int cb = (lane & 31) * 16;
        gld_lds16(zb + (size_t)glist[row] * 512 + (cb ^ ((row & 7) << 4)),
                  (char*)Zc + e2 * 512);
    }
    __syncthreads();                           // vmcnt drained by barrier

    // ---- pass 1: sum_same ----
    for (int mi = w; mi < nt; mi += 8) {
        const int rowA = mi * 16 + l15;
        const int swa = (rowA & 7) << 4;
        bf16x8 a[8];
#pragma unroll
        for (int kf = 0; kf < 8; ++kf)
            a[kf] = *(const bf16x8*)(Zc + rowA * 512 + ((lk * 16 + kf * 64) ^ swa));
        float sp[4] = {};
        for (int nj = 0; nj < nt; ++nj) {
            const int colB = nj * 16 + l15;
            const int swb = (colB & 7) << 4;
            bf16x8 b[8];
#pragma unroll
            for (int kf = 0; kf < 8; ++kf)
                b[kf] = *(const bf16x8*)(Zc + colB * 512 + ((lk * 16 + kf * 64) ^ swb));
            f32x4 acc = {};
#pragma unroll
            for (int kf = 0; kf < 8; ++kf)
                acc = __builtin_amdgcn_mfma_f32_16x16x32_bf16(a[kf], b[kf], acc, 0, 0, 0);
#pragma unroll
            for (int rr = 0; rr < 4; ++rr) {
                const int i = mi * 16 + lk * 4 + rr;
                const float e = __expf(acc[rr] * INV_T);
                sp[rr] += (colB < n_c && i != colB) ? e : 0.f;
            }
        }
#pragma unroll
        for (int rr = 0; rr < 4; ++rr) {
            float v = sp[rr];
            v += __shfl_xor(v, 1, 64);
            v += __shfl_xor(v, 2, 64);
            v += __shfl_xor(v, 4, 64);
            v += __shfl_xor(v, 8, 64);
            if (l15 == 0) sums[mi * 16 + lk * 4 + rr] = v;
        }
    }
    __syncthreads();
    if (tid < CAP)
        snl[tid] = (tid < n_c)
            ? (sn_part[glist[tid]] + sn_part[BN + glist[tid]]
               + sn_part[2 * BN + glist[tid]] + sn_part[3 * BN + glist[tid]]
               - sums[tid])
            : 0.f;
    __syncthreads();

    // ---- pass 2: pair losses ----
    for (int mi = w; mi < nt; mi += 8) {
        const int rowA = mi * 16 + l15;
        const int swa = (rowA & 7) << 4;
        bf16x8 a[8];
#pragma unroll
        for (int kf = 0; kf < 8; ++kf)
            a[kf] = *(const bf16x8*)(Zc + rowA * 512 + ((lk * 16 + kf * 64) ^ swa));
        float sneg[4];
#pragma unroll
        for (int rr = 0; rr < 4; ++rr) {
            const int i = mi * 16 + lk * 4 + rr;
            sneg[rr] = (i < n_c) ? snl[i] : 0.f;
        }
        float sp[4] = {};
        for (int nj = 0; nj < nt; ++nj) {
            const int colB = nj * 16 + l15;
            const int swb = (colB & 7) << 4;
            bf16x8 b[8];
#pragma unroll
            for (int kf = 0; kf < 8; ++kf)
                b[kf] = *(const bf16x8*)(Zc + colB * 512 + ((lk * 16 + kf * 64) ^ swb));
            f32x4 acc = {};
#pragma unroll
            for (int kf = 0; kf < 8; ++kf)
                acc = __builtin_amdgcn_mfma_f32_16x16x32_bf16(a[kf], b[kf], acc, 0, 0, 0);
#pragma unroll
            for (int rr = 0; rr < 4; ++rr) {
                const int i = mi * 16 + lk * 4 + rr;
                const float t = log1pf(sneg[rr] * __expf(-acc[rr] * INV_T));
                sp[rr] += (colB < n_c && i != colB) ? t : 0.f;
            }
        }
#pragma unroll
        for (int rr = 0; rr < 4; ++rr) {
            float v = sp[rr];
            v += __shfl_xor(v, 1, 64);
            v += __shfl_xor(v, 2, 64);
            v += __shfl_xor(v, 4, 64);
            v += __shfl_xor(v, 8, 64);
            const int i = mi * 16 + lk * 4 + rr;
            if (l15 == 0 && i < n_c && n_c > 1)
                atomicAdd(&blkL, v / (float)(n_c - 1));
        }
    }
    __syncthreads();
    if (tid == 0 && n_c > 1) {
        atomicAdd(&gacc[0], blkL);
        atomicAdd(&gacc[1], (float)n_c);
    }
}

// ---------------- kernel 4: final scalar ----------------------------------
__global__ void k_final(const float* __restrict__ gacc, float* __restrict__ out) {
    if (threadIdx.x == 0) {
        const float L = gacc[0], V = gacc[1];
        out[0] = (V > 0.f) ? L / fmaxf(V, 1.f) : 0.f;
    }
}

extern "C" void kernel_launch(void* const* d_in, const int* in_sizes, int n_in,
                              void* d_out, int out_size, void* d_ws, size_t ws_size,
                              hipStream_t stream) {
    const float* z      = (const float*)d_in[0];
    const int*   labels = (const int*)d_in[1];
    float* out = (float*)d_out;

    char* ws = (char*)d_ws;
    // zbf 4MB | sn_part 4x8192 f32 | cls_cnt 1KB | cls_idx 100KB | gacc 8B
    unsigned short* zbf = (unsigned short*)ws;
    size_t off = (size_t)BN * DD * sizeof(unsigned short);
    float* sn_part = (float*)(ws + off);  off += 4 * BN * sizeof(float);
    int*   cls_cnt = (int*)(ws + off);    off += 1024;
    int*   cls_idx = (int*)(ws + off);    off += 100 * CAPI * sizeof(int);
    float* gacc    = (float*)(ws + off);  off += 2 * sizeof(float);

    k_prep  <<<1024, 256, 0, stream>>>(z, zbf, cls_cnt, gacc);
    k_bucket<<<32, 256, 0, stream>>>(labels, cls_cnt, cls_idx);
    k_passA <<<256, 512, 0, stream>>>(zbf, sn_part);
    k_passB <<<100, 512, 0, stream>>>(zbf, sn_part, cls_cnt, cls_idx, gacc);
    k_final <<<1, 64, 0, stream>>>(gacc, out);
}